// Round 1
// baseline (639.640 us; speedup 1.0000x reference)
//
#include <hip/hip_runtime.h>
#include <hip/hip_bf16.h>

#define NUM_CLASSES 200
#define NUM_FEATURES 128
#define NUM_PROTOTYPES 2000
#define HW 196           // 14*14
#define NBATCH 64
#define EPSV 1e-4f

// ---------------- kernel 0a: x_sq[n][hw] = sum_d f[n][d][hw]^2 ----------------
__global__ __launch_bounds__(256) void kxsq(const float* __restrict__ f, float* __restrict__ xsq) {
    int n = blockIdx.x, t = threadIdx.x;
    if (t < HW) {
        const float* fn = f + (size_t)n * NUM_FEATURES * HW;
        float s = 0.f;
        #pragma unroll 4
        for (int d = 0; d < NUM_FEATURES; ++d) {
            float v = fn[d * HW + t];
            s += v * v;
        }
        xsq[n * HW + t] = s;
    }
}

// ---------------- kernel 0b: p_sq[p] (padded to 2048, zeros past 2000) --------
__global__ __launch_bounds__(256) void kpsq(const float* __restrict__ protos, float* __restrict__ psq) {
    int p = blockIdx.x * 256 + threadIdx.x;   // grid 8 -> 2048
    float s = 0.f;
    if (p < NUM_PROTOTYPES) {
        const float* r = protos + (size_t)p * NUM_FEATURES;
        #pragma unroll
        for (int d = 0; d < NUM_FEATURES; d += 4) {
            float4 v = *(const float4*)(r + d);
            s += v.x * v.x + v.y * v.y + v.z * v.z + v.w * v.w;
        }
    }
    psq[p] = s;
}

// ---------------- kernel 1: min-distance GEMM ---------------------------------
// grid (32 proto-tiles, 64 n), block 256 = 16(tx: proto grp) x 16(ty: hw grp)
// per-thread 4x4; B (64p x 128k) fully LDS-resident; A staged 32k x 64hw.
__global__ __launch_bounds__(256) void kdist(const float* __restrict__ f,
                                             const float* __restrict__ protos,
                                             const float* __restrict__ xsq,
                                             const float* __restrict__ psq,
                                             float* __restrict__ min_out) {
    __shared__ float sb[128][64];   // [k][p_local]  32 KB
    __shared__ float sa[32][64];    // [k][hw_local]  8 KB
    __shared__ float red[16][64];   // reduction      4 KB

    const int n  = blockIdx.y;
    const int p0 = blockIdx.x * 64;
    const int t  = threadIdx.x;

    // ---- stage B once: protos[p0+pl][k] -> sb[k][pl]
    {
        int pl = t >> 2;            // 0..63
        int k4 = (t & 3) * 4;       // 0,4,8,12
        const float* src = protos + (size_t)(p0 + pl) * NUM_FEATURES;
        bool valid = (p0 + pl) < NUM_PROTOTYPES;
        #pragma unroll
        for (int j = 0; j < 8; ++j) {
            int k = j * 16 + k4;
            float4 v = valid ? *(const float4*)(src + k) : make_float4(0.f, 0.f, 0.f, 0.f);
            sb[k + 0][pl] = v.x;
            sb[k + 1][pl] = v.y;
            sb[k + 2][pl] = v.z;
            sb[k + 3][pl] = v.w;
        }
    }

    const int tx = t & 15;          // proto group: protos tx*4 .. tx*4+3
    const int ty = t >> 4;          // hw group:    hw    ty*4 .. ty*4+3
    const float* fn = f + (size_t)n * NUM_FEATURES * HW;

    float minv[4] = {3.0e38f, 3.0e38f, 3.0e38f, 3.0e38f};

    for (int hwt = 0; hwt < 4; ++hwt) {
        const int hw0 = hwt * 64;
        float acc[4][4];
        #pragma unroll
        for (int i = 0; i < 4; ++i)
            #pragma unroll
            for (int j = 0; j < 4; ++j) acc[i][j] = 0.f;

        for (int kc = 0; kc < 4; ++kc) {
            const int k0 = kc * 32;
            __syncthreads();
            // ---- stage A chunk: f[n][k0+kk][hw0+hh] -> sa[kk][hh]
            {
                int kk = t >> 4;            // 0..15
                int hh = (t & 15) * 4;      // 0..60
                #pragma unroll
                for (int h = 0; h < 2; ++h) {
                    int kkk = kk + h * 16;
                    int hw = hw0 + hh;      // multiple of 4; all-4-valid or all-4-invalid
                    float4 v = (hw < HW) ? *(const float4*)(fn + (k0 + kkk) * HW + hw)
                                         : make_float4(0.f, 0.f, 0.f, 0.f);
                    *(float4*)&sa[kkk][hh] = v;
                }
            }
            __syncthreads();
            // ---- compute
            #pragma unroll
            for (int kk = 0; kk < 32; ++kk) {
                float4 a4 = *(const float4*)&sa[kk][ty * 4];
                float4 b4 = *(const float4*)&sb[k0 + kk][tx * 4];
                float a[4] = {a4.x, a4.y, a4.z, a4.w};
                float b[4] = {b4.x, b4.y, b4.z, b4.w};
                #pragma unroll
                for (int i = 0; i < 4; ++i)
                    #pragma unroll
                    for (int j = 0; j < 4; ++j)
                        acc[i][j] = fmaf(a[i], b[j], acc[i][j]);
            }
        }

        // ---- epilogue for this hw tile: dist = xsq + psq - 2*xp, relu, min
        #pragma unroll
        for (int i = 0; i < 4; ++i) {
            int hw = hw0 + ty * 4 + i;
            if (hw < HW) {
                float xs = xsq[n * HW + hw];
                #pragma unroll
                for (int j = 0; j < 4; ++j) {
                    float dd = xs + psq[p0 + tx * 4 + j] - 2.f * acc[i][j];
                    dd = fmaxf(dd, 0.f);
                    minv[j] = fminf(minv[j], dd);
                }
            }
        }
    }

    // ---- reduce min across the 16 hw-thread-groups
    __syncthreads();
    #pragma unroll
    for (int j = 0; j < 4; ++j) red[ty][tx * 4 + j] = minv[j];
    __syncthreads();
    if (t < 64) {
        float m = red[0][t];
        #pragma unroll
        for (int r = 1; r < 16; ++r) m = fminf(m, red[r][t]);
        int p = p0 + t;
        if (p < NUM_PROTOTYPES) min_out[n * NUM_PROTOTYPES + p] = m;
    }
}

// ---------------- kernel 2: sim = log((md+1)/(md+eps)); logits = sim @ W^T ----
__global__ __launch_bounds__(256) void klogits(const float* __restrict__ md,
                                               const float* __restrict__ W,
                                               float* __restrict__ logits) {
    __shared__ float ssim[NUM_PROTOTYPES];
    int n = blockIdx.x, t = threadIdx.x;
    for (int p = t; p < NUM_PROTOTYPES; p += 256) {
        float d = md[n * NUM_PROTOTYPES + p];
        ssim[p] = logf((d + 1.f) / (d + EPSV));
    }
    __syncthreads();
    int wave = t >> 6, lane = t & 63;
    for (int c = wave; c < NUM_CLASSES; c += 4) {
        float acc = 0.f;
        const float* wr = W + (size_t)c * NUM_PROTOTYPES;
        for (int p = lane; p < NUM_PROTOTYPES; p += 64)
            acc += ssim[p] * wr[p];
        #pragma unroll
        for (int off = 32; off; off >>= 1) acc += __shfl_down(acc, off, 64);
        if (lane == 0) logits[n * NUM_CLASSES + c] = acc;
    }
}

extern "C" void kernel_launch(void* const* d_in, const int* in_sizes, int n_in,
                              void* d_out, int out_size, void* d_ws, size_t ws_size,
                              hipStream_t stream) {
    const float* f      = (const float*)d_in[0];  // 64x128x14x14
    const float* protos = (const float*)d_in[1];  // 2000x128 (x1x1)
    const float* W      = (const float*)d_in[2];  // 200x2000

    float* logits   = (float*)d_out;                          // 64*200
    float* min_dist = (float*)d_out + NBATCH * NUM_CLASSES;   // 64*2000

    float* xsq = (float*)d_ws;                // 64*196 = 12544 floats
    float* psq = xsq + NBATCH * HW;           // 2048 floats (padded)

    kxsq<<<NBATCH, 256, 0, stream>>>(f, xsq);
    kpsq<<<8, 256, 0, stream>>>(protos, psq);
    kdist<<<dim3(32, NBATCH), 256, 0, stream>>>(f, protos, xsq, psq, min_dist);
    klogits<<<NBATCH, 256, 0, stream>>>(min_dist, W, logits);
}

// Round 2
// 194.446 us; speedup vs baseline: 3.2895x; 3.2895x over previous
//
#include <hip/hip_runtime.h>
#include <hip/hip_bf16.h>

#define NUM_CLASSES 200
#define NUM_FEATURES 128
#define NUM_PROTOTYPES 2000
#define HW 196           // 14*14
#define NBATCH 64
#define EPSV 1e-4f

// ---------------- kernel 0: fused x_sq (blocks 0..63) + p_sq (blocks 64..71) --
__global__ __launch_bounds__(256) void kpre(const float* __restrict__ f,
                                            const float* __restrict__ protos,
                                            float* __restrict__ xsq,
                                            float* __restrict__ psq) {
    int b = blockIdx.x, t = threadIdx.x;
    if (b < NBATCH) {
        if (t < HW) {
            const float* fn = f + (size_t)b * NUM_FEATURES * HW;
            float s = 0.f;
            #pragma unroll 4
            for (int d = 0; d < NUM_FEATURES; ++d) {
                float v = fn[d * HW + t];
                s += v * v;
            }
            xsq[b * HW + t] = s;
        }
    } else {
        int p = (b - NBATCH) * 256 + t;   // 0..2047
        float s = 0.f;
        if (p < NUM_PROTOTYPES) {
            const float* r = protos + (size_t)p * NUM_FEATURES;
            #pragma unroll
            for (int d = 0; d < NUM_FEATURES; d += 4) {
                float4 v = *(const float4*)(r + d);
                s += v.x * v.x + v.y * v.y + v.z * v.z + v.w * v.w;
            }
        }
        psq[p] = s;
    }
}

// ---------------- kernel 1: min-distance GEMM + fused sim --------------------
// grid (32 proto-tiles, 64 n), block 256 = 16(tx: proto grp) x 16(ty: hw grp)
// per-thread 4x4; B (64p x 128k) fully LDS-resident; A staged 32k x 64hw.
__global__ __launch_bounds__(256) void kdist(const float* __restrict__ f,
                                             const float* __restrict__ protos,
                                             const float* __restrict__ xsq,
                                             const float* __restrict__ psq,
                                             float* __restrict__ min_out,
                                             float* __restrict__ sim_out) {
    __shared__ float sb[128][64];   // [k][p_local]  32 KB
    __shared__ float sa[32][64];    // [k][hw_local]  8 KB
    __shared__ float red[16][64];   // reduction      4 KB

    const int n  = blockIdx.y;
    const int p0 = blockIdx.x * 64;
    const int t  = threadIdx.x;

    // ---- stage B once: protos[p0+pl][k] -> sb[k][pl]
    {
        int pl = t >> 2;            // 0..63
        int k4 = (t & 3) * 4;       // 0,4,8,12
        const float* src = protos + (size_t)(p0 + pl) * NUM_FEATURES;
        bool valid = (p0 + pl) < NUM_PROTOTYPES;
        #pragma unroll
        for (int j = 0; j < 8; ++j) {
            int k = j * 16 + k4;
            float4 v = valid ? *(const float4*)(src + k) : make_float4(0.f, 0.f, 0.f, 0.f);
            sb[k + 0][pl] = v.x;
            sb[k + 1][pl] = v.y;
            sb[k + 2][pl] = v.z;
            sb[k + 3][pl] = v.w;
        }
    }

    const int tx = t & 15;          // proto group: protos tx*4 .. tx*4+3
    const int ty = t >> 4;          // hw group:    hw    ty*4 .. ty*4+3
    const float* fn = f + (size_t)n * NUM_FEATURES * HW;

    float minv[4] = {3.0e38f, 3.0e38f, 3.0e38f, 3.0e38f};

    for (int hwt = 0; hwt < 4; ++hwt) {
        const int hw0 = hwt * 64;
        float acc[4][4];
        #pragma unroll
        for (int i = 0; i < 4; ++i)
            #pragma unroll
            for (int j = 0; j < 4; ++j) acc[i][j] = 0.f;

        for (int kc = 0; kc < 4; ++kc) {
            const int k0 = kc * 32;
            __syncthreads();
            // ---- stage A chunk: f[n][k0+kk][hw0+hh] -> sa[kk][hh]
            {
                int kk = t >> 4;            // 0..15
                int hh = (t & 15) * 4;      // 0..60
                #pragma unroll
                for (int h = 0; h < 2; ++h) {
                    int kkk = kk + h * 16;
                    int hw = hw0 + hh;      // multiple of 4; all-4-valid or all-4-invalid
                    float4 v = (hw < HW) ? *(const float4*)(fn + (k0 + kkk) * HW + hw)
                                         : make_float4(0.f, 0.f, 0.f, 0.f);
                    *(float4*)&sa[kkk][hh] = v;
                }
            }
            __syncthreads();
            // ---- compute
            #pragma unroll
            for (int kk = 0; kk < 32; ++kk) {
                float4 a4 = *(const float4*)&sa[kk][ty * 4];
                float4 b4 = *(const float4*)&sb[k0 + kk][tx * 4];
                float a[4] = {a4.x, a4.y, a4.z, a4.w};
                float b[4] = {b4.x, b4.y, b4.z, b4.w};
                #pragma unroll
                for (int i = 0; i < 4; ++i)
                    #pragma unroll
                    for (int j = 0; j < 4; ++j)
                        acc[i][j] = fmaf(a[i], b[j], acc[i][j]);
            }
        }

        // ---- epilogue for this hw tile: dist = xsq + psq - 2*xp, relu, min
        #pragma unroll
        for (int i = 0; i < 4; ++i) {
            int hw = hw0 + ty * 4 + i;
            if (hw < HW) {
                float xs = xsq[n * HW + hw];
                #pragma unroll
                for (int j = 0; j < 4; ++j) {
                    float dd = xs + psq[p0 + tx * 4 + j] - 2.f * acc[i][j];
                    dd = fmaxf(dd, 0.f);
                    minv[j] = fminf(minv[j], dd);
                }
            }
        }
    }

    // ---- reduce min across the 16 hw-thread-groups; write min_dist AND sim
    __syncthreads();
    #pragma unroll
    for (int j = 0; j < 4; ++j) red[ty][tx * 4 + j] = minv[j];
    __syncthreads();
    if (t < 64) {
        float m = red[0][t];
        #pragma unroll
        for (int r = 1; r < 16; ++r) m = fminf(m, red[r][t]);
        int p = p0 + t;
        if (p < NUM_PROTOTYPES) {
            min_out[n * NUM_PROTOTYPES + p] = m;
            // sim is decreasing in dist => sim_max = sim(min_dist)
            sim_out[n * NUM_PROTOTYPES + p] = logf((m + 1.f) / (m + EPSV));
        }
    }
}

// ---------------- kernel 2: logits[n][c] = sum_p sim[n][p] * W[c][p] ---------
// one wave per (n, c): grid (64, 50), block 256 = 4 waves (4 classes)
__global__ __launch_bounds__(256) void klogits(const float* __restrict__ sim,
                                               const float* __restrict__ W,
                                               float* __restrict__ logits) {
    const int n    = blockIdx.x;
    const int wave = threadIdx.x >> 6;
    const int lane = threadIdx.x & 63;
    const int c    = blockIdx.y * 4 + wave;       // 0..199

    const float* s  = sim + (size_t)n * NUM_PROTOTYPES;
    const float* wr = W + (size_t)c * NUM_PROTOTYPES;

    float acc = 0.f;
    #pragma unroll 4
    for (int p = lane; p < NUM_PROTOTYPES; p += 64)
        acc += s[p] * wr[p];
    #pragma unroll
    for (int off = 32; off; off >>= 1) acc += __shfl_down(acc, off, 64);
    if (lane == 0) logits[n * NUM_CLASSES + c] = acc;
}

extern "C" void kernel_launch(void* const* d_in, const int* in_sizes, int n_in,
                              void* d_out, int out_size, void* d_ws, size_t ws_size,
                              hipStream_t stream) {
    const float* f      = (const float*)d_in[0];  // 64x128x14x14
    const float* protos = (const float*)d_in[1];  // 2000x128 (x1x1)
    const float* W      = (const float*)d_in[2];  // 200x2000

    float* logits   = (float*)d_out;                          // 64*200
    float* min_dist = (float*)d_out + NBATCH * NUM_CLASSES;   // 64*2000

    float* xsq = (float*)d_ws;                  // 64*196 floats
    float* psq = xsq + NBATCH * HW;             // 2048 floats (padded)
    float* sim = psq + 2048;                    // 64*2000 floats

    kpre<<<NBATCH + 8, 256, 0, stream>>>(f, protos, xsq, psq);
    kdist<<<dim3(32, NBATCH), 256, 0, stream>>>(f, protos, xsq, psq, min_dist, sim);
    klogits<<<dim3(NBATCH, 50), 256, 0, stream>>>(sim, W, logits);
}

// Round 3
// 141.220 us; speedup vs baseline: 4.5294x; 1.3769x over previous
//
#include <hip/hip_runtime.h>
#include <hip/hip_bf16.h>

#define NUM_CLASSES 200
#define NF 128
#define NP 2000
#define NP_PAD 2048
#define HW 196
#define MPAD 208      // 13 * 16
#define NB 64
#define EPSV 1e-4f

typedef __attribute__((ext_vector_type(8))) short short8;   // 8 bf16 = 4 VGPR
typedef __attribute__((ext_vector_type(4))) float f32x4;

static __device__ __forceinline__ unsigned short f2bf(float x) {
    __hip_bfloat16 h = __float2bfloat16(x);
    return __builtin_bit_cast(unsigned short, h);
}

// ---- kernel 0: xsq (blocks 0..63) | pT bf16 convert (64..191) | psq (192..199)
__global__ __launch_bounds__(256) void kpre(const float* __restrict__ f,
                                            const float* __restrict__ protos,
                                            float* __restrict__ xsq,
                                            float* __restrict__ psq,
                                            unsigned short* __restrict__ pT) {
    int b = blockIdx.x, t = threadIdx.x;
    if (b < NB) {
        if (t < HW) {
            const float* fn = f + (size_t)b * NF * HW;
            float s = 0.f;
            #pragma unroll 4
            for (int d = 0; d < NF; ++d) {
                float v = fn[d * HW + t];
                s += v * v;
            }
            xsq[b * HW + t] = s;
        }
    } else if (b < NB + 128) {
        // bf16 convert of prototypes: 2048 rows x 16 chunks of 8
        int idx = (b - NB) * 256 + t;        // 0 .. 32767
        int p  = idx >> 4;
        int kc = (idx & 15) * 8;
        unsigned short u[8];
        if (p < NP) {
            const float* src = protos + (size_t)p * NF + kc;
            float4 v0 = *(const float4*)(src);
            float4 v1 = *(const float4*)(src + 4);
            u[0] = f2bf(v0.x); u[1] = f2bf(v0.y); u[2] = f2bf(v0.z); u[3] = f2bf(v0.w);
            u[4] = f2bf(v1.x); u[5] = f2bf(v1.y); u[6] = f2bf(v1.z); u[7] = f2bf(v1.w);
        } else {
            #pragma unroll
            for (int j = 0; j < 8; ++j) u[j] = 0;
        }
        *(uint4*)(pT + (size_t)p * NF + kc) = *(uint4*)u;
    } else {
        int p = (b - NB - 128) * 256 + t;    // 0..2047
        float s = 0.f;
        if (p < NP) {
            const float* r = protos + (size_t)p * NF;
            #pragma unroll
            for (int d = 0; d < NF; d += 4) {
                float4 v = *(const float4*)(r + d);
                s += v.x * v.x + v.y * v.y + v.z * v.z + v.w * v.w;
            }
        }
        psq[p] = s;
    }
}

// ---- kernel 1: transpose+convert f[n][k][hw] -> fT[n][hw(pad208)][k] bf16 ----
// grid (13 hw-tiles, 64 n), 256 threads
__global__ __launch_bounds__(256) void kprep_f(const float* __restrict__ f,
                                               unsigned short* __restrict__ fT) {
    __shared__ float tile[NF][21];   // [k][hw_local], pad to break conflicts
    const int hw0 = blockIdx.x * 16;
    const int n   = blockIdx.y;
    const int t   = threadIdx.x;

    // load: thread -> k = (t>>2) + 64*i, hw_local = (t&3)*4
    {
        int kb  = t >> 2;
        int hwl = (t & 3) * 4;
        int hw  = hw0 + hwl;
        bool valid = hw < HW;              // HW=196 is a multiple of 4
        #pragma unroll
        for (int i = 0; i < 2; ++i) {
            int k = kb + 64 * i;
            float4 v = valid ? *(const float4*)(f + ((size_t)n * NF + k) * HW + hw)
                             : make_float4(0.f, 0.f, 0.f, 0.f);
            tile[k][hwl + 0] = v.x;
            tile[k][hwl + 1] = v.y;
            tile[k][hwl + 2] = v.z;
            tile[k][hwl + 3] = v.w;
        }
    }
    __syncthreads();
    // store: thread -> row hw_local = t>>4, k-chunk = (t&15)*8
    {
        int hwl = t >> 4;
        int kc  = (t & 15) * 8;
        unsigned short u[8];
        #pragma unroll
        for (int j = 0; j < 8; ++j) u[j] = f2bf(tile[kc + j][hwl]);
        size_t row = (size_t)n * MPAD + hw0 + hwl;
        *(uint4*)(fT + row * NF + kc) = *(uint4*)u;
    }
}

// ---- kernel 2: MFMA distance + min + fused sim -------------------------------
// grid (32 p-tiles of 64, 64 n), 4 waves; wave w -> 16 protos.
// D[m=p_local][nD=hw_local]; A = protos (pT), B = features (fT). No LDS.
__global__ __launch_bounds__(256) void kdist(const unsigned short* __restrict__ pT,
                                             const unsigned short* __restrict__ fT,
                                             const float* __restrict__ xsq,
                                             const float* __restrict__ psq,
                                             float* __restrict__ min_out,
                                             float* __restrict__ sim_out) {
    const int n    = blockIdx.y;
    const int wave = threadIdx.x >> 6;
    const int lane = threadIdx.x & 63;
    const int row  = lane & 15;          // m/n index within frag
    const int quad = lane >> 4;          // k-chunk selector
    const int pb   = blockIdx.x * 64 + wave * 16;   // this wave's 16 protos

    // A frags: protos[pb+row][quad*8 + kk*32 + j]
    const unsigned short* ap = pT + (size_t)(pb + row) * NF + quad * 8;
    short8 a0 = *(const short8*)(ap);
    short8 a1 = *(const short8*)(ap + 32);
    short8 a2 = *(const short8*)(ap + 64);
    short8 a3 = *(const short8*)(ap + 96);

    // psq for this lane's 4 D-rows (p = pb + quad*4 + r)
    float psq_r[4];
    #pragma unroll
    for (int r = 0; r < 4; ++r) psq_r[r] = psq[pb + quad * 4 + r];

    const unsigned short* fb = fT + (size_t)n * MPAD * NF + quad * 8;
    const float* xs_n = xsq + n * HW;

    float runmin[4] = {3.0e38f, 3.0e38f, 3.0e38f, 3.0e38f};

    for (int mt = 0; mt < 13; ++mt) {
        const int hw = mt * 16 + row;    // this lane's D column
        const unsigned short* bp = fb + (size_t)(mt * 16 + row) * NF;
        short8 b0 = *(const short8*)(bp);
        short8 b1 = *(const short8*)(bp + 32);
        short8 b2 = *(const short8*)(bp + 64);
        short8 b3 = *(const short8*)(bp + 96);

        f32x4 acc = {0.f, 0.f, 0.f, 0.f};
        acc = __builtin_amdgcn_mfma_f32_16x16x32_bf16(a0, b0, acc, 0, 0, 0);
        acc = __builtin_amdgcn_mfma_f32_16x16x32_bf16(a1, b1, acc, 0, 0, 0);
        acc = __builtin_amdgcn_mfma_f32_16x16x32_bf16(a2, b2, acc, 0, 0, 0);
        acc = __builtin_amdgcn_mfma_f32_16x16x32_bf16(a3, b3, acc, 0, 0, 0);

        float xv = (hw < HW) ? xs_n[hw] : 3.0e38f;   // invalid cols can't win
        #pragma unroll
        for (int r = 0; r < 4; ++r)
            runmin[r] = fminf(runmin[r], xv - 2.f * acc[r]);
    }

    // min across the 16 columns (lanes sharing a quad)
    #pragma unroll
    for (int off = 1; off < 16; off <<= 1) {
        #pragma unroll
        for (int r = 0; r < 4; ++r)
            runmin[r] = fminf(runmin[r], __shfl_xor(runmin[r], off, 64));
    }

    if (row == 0) {
        #pragma unroll
        for (int r = 0; r < 4; ++r) {
            int p = pb + quad * 4 + r;
            if (p < NP) {
                float m = fmaxf(runmin[r] + psq_r[r], 0.f);
                min_out[(size_t)n * NP + p] = m;
                sim_out[(size_t)n * NP + p] = logf((m + 1.f) / (m + EPSV));
            }
        }
    }
}

// ---- kernel 3: logits[n][c] = sum_p sim[n][p] * W[c][p] ----------------------
__global__ __launch_bounds__(256) void klogits(const float* __restrict__ sim,
                                               const float* __restrict__ W,
                                               float* __restrict__ logits) {
    const int n    = blockIdx.x;
    const int wave = threadIdx.x >> 6;
    const int lane = threadIdx.x & 63;
    const int c    = blockIdx.y * 4 + wave;

    const float* s  = sim + (size_t)n * NP;
    const float* wr = W + (size_t)c * NP;

    float acc = 0.f;
    #pragma unroll 4
    for (int p = lane; p < NP; p += 64)
        acc += s[p] * wr[p];
    #pragma unroll
    for (int off = 32; off; off >>= 1) acc += __shfl_down(acc, off, 64);
    if (lane == 0) logits[n * NUM_CLASSES + c] = acc;
}

extern "C" void kernel_launch(void* const* d_in, const int* in_sizes, int n_in,
                              void* d_out, int out_size, void* d_ws, size_t ws_size,
                              hipStream_t stream) {
    const float* f      = (const float*)d_in[0];  // 64x128x14x14
    const float* protos = (const float*)d_in[1];  // 2000x128
    const float* W      = (const float*)d_in[2];  // 200x2000

    float* logits   = (float*)d_out;
    float* min_dist = (float*)d_out + NB * NUM_CLASSES;

    float* xsq = (float*)d_ws;                       // 64*196 f32
    float* psq = xsq + NB * HW;                      // 2048 f32
    float* sim = psq + NP_PAD;                       // 64*2000 f32
    unsigned short* pT = (unsigned short*)(sim + NB * NP);   // 2048*128 bf16
    unsigned short* fT = pT + (size_t)NP_PAD * NF;           // 64*208*128 bf16

    kpre<<<NB + 128 + 8, 256, 0, stream>>>(f, protos, xsq, psq, pT);
    kprep_f<<<dim3(13, NB), 256, 0, stream>>>(f, fT);
    kdist<<<dim3(32, NB), 256, 0, stream>>>(pT, fT, xsq, psq, min_dist, sim);
    klogits<<<dim3(NB, 50), 256, 0, stream>>>(sim, W, logits);
}

// Round 4
// 101.594 us; speedup vs baseline: 6.2960x; 1.3900x over previous
//
#include <hip/hip_runtime.h>
#include <hip/hip_bf16.h>

#define NUM_CLASSES 200
#define NF 128
#define NP 2000
#define NP_PAD 2048
#define HW 196
#define MPAD 208        // 13 * 16
#define NB 64
#define EPSV 1e-4f
#define LDS_ROW 136     // 128 shorts + 8 pad (272 B) -> 2-way bank conflicts only

typedef __attribute__((ext_vector_type(8))) short short8;   // 8 bf16 = 4 VGPR
typedef __attribute__((ext_vector_type(4))) float f32x4;

static __device__ __forceinline__ unsigned short f2bf(float x) {
    __hip_bfloat16 h = __float2bfloat16(x);
    return __builtin_bit_cast(unsigned short, h);
}

// ---- kernel 0 (merged prep): grid 832 + 64 + 128 + 8 = 1032 blocks ----------
// [0,832)   : transpose+convert f[n][k][hw] -> fT[n][hw(pad208)][k] bf16
// [832,896) : xsq[n][hw]
// [896,1024): pT bf16 convert (2048 x 128)
// [1024,1032): psq
__global__ __launch_bounds__(256) void kprep(const float* __restrict__ f,
                                             const float* __restrict__ protos,
                                             float* __restrict__ xsq,
                                             float* __restrict__ psq,
                                             unsigned short* __restrict__ pT,
                                             unsigned short* __restrict__ fT) {
    __shared__ float tile[NF][21];
    const int b = blockIdx.x, t = threadIdx.x;
    if (b < 832) {
        const int hw0 = (b % 13) * 16;
        const int n   = b / 13;
        {
            int kb  = t >> 2;
            int hwl = (t & 3) * 4;
            int hw  = hw0 + hwl;
            bool valid = hw < HW;          // HW=196 is a multiple of 4
            #pragma unroll
            for (int i = 0; i < 2; ++i) {
                int k = kb + 64 * i;
                float4 v = valid ? *(const float4*)(f + ((size_t)n * NF + k) * HW + hw)
                                 : make_float4(0.f, 0.f, 0.f, 0.f);
                tile[k][hwl + 0] = v.x;
                tile[k][hwl + 1] = v.y;
                tile[k][hwl + 2] = v.z;
                tile[k][hwl + 3] = v.w;
            }
        }
        __syncthreads();
        {
            int hwl = t >> 4;
            int kc  = (t & 15) * 8;
            unsigned short u[8];
            #pragma unroll
            for (int j = 0; j < 8; ++j) u[j] = f2bf(tile[kc + j][hwl]);
            size_t row = (size_t)n * MPAD + hw0 + hwl;
            *(uint4*)(fT + row * NF + kc) = *(uint4*)u;
        }
    } else if (b < 896) {
        int n = b - 832;
        if (t < HW) {
            const float* fn = f + (size_t)n * NF * HW;
            float s = 0.f;
            #pragma unroll 4
            for (int d = 0; d < NF; ++d) {
                float v = fn[d * HW + t];
                s += v * v;
            }
            xsq[n * HW + t] = s;
        }
    } else if (b < 1024) {
        int idx = (b - 896) * 256 + t;     // 0 .. 32767
        int p  = idx >> 4;
        int kc = (idx & 15) * 8;
        unsigned short u[8];
        if (p < NP) {
            const float* src = protos + (size_t)p * NF + kc;
            float4 v0 = *(const float4*)(src);
            float4 v1 = *(const float4*)(src + 4);
            u[0] = f2bf(v0.x); u[1] = f2bf(v0.y); u[2] = f2bf(v0.z); u[3] = f2bf(v0.w);
            u[4] = f2bf(v1.x); u[5] = f2bf(v1.y); u[6] = f2bf(v1.z); u[7] = f2bf(v1.w);
        } else {
            #pragma unroll
            for (int j = 0; j < 8; ++j) u[j] = 0;
        }
        *(uint4*)(pT + (size_t)p * NF + kc) = *(uint4*)u;
    } else {
        int p = (b - 1024) * 256 + t;      // 0..2047
        float s = 0.f;
        if (p < NP) {
            const float* r = protos + (size_t)p * NF;
            #pragma unroll
            for (int d = 0; d < NF; d += 4) {
                float4 v = *(const float4*)(r + d);
                s += v.x * v.x + v.y * v.y + v.z * v.z + v.w * v.w;
            }
        }
        psq[p] = s;
    }
}

// ---- kernel 1: MFMA distance + min + fused sim -------------------------------
// grid (64 n, 8 p-tiles) [n fastest -> same-n blocks co-locate per XCD].
// Block: 4 waves; wave w -> 64 protos (4 groups of 16). fT[n] staged in LDS.
__global__ __launch_bounds__(256) void kdist(const unsigned short* __restrict__ pT,
                                             const unsigned short* __restrict__ fT,
                                             const float* __restrict__ xsq,
                                             const float* __restrict__ psq,
                                             float* __restrict__ min_out,
                                             float* __restrict__ sim_out) {
    __shared__ unsigned short sf[MPAD * LDS_ROW];   // 56,576 B -> 2 blocks/CU

    const int n    = blockIdx.x;
    const int pt   = blockIdx.y;
    const int t    = threadIdx.x;
    const int wave = t >> 6;
    const int lane = t & 63;
    const int row  = lane & 15;
    const int quad = lane >> 4;
    const int pb   = pt * 256 + wave * 64;

    // A frags: 4 proto-groups x 4 k-chunks (issued first, consumed after barrier)
    short8 A[4][4];
    {
        const unsigned short* ap = pT + (size_t)(pb + row) * NF + quad * 8;
        #pragma unroll
        for (int g = 0; g < 4; ++g)
            #pragma unroll
            for (int kk = 0; kk < 4; ++kk)
                A[g][kk] = *(const short8*)(ap + (size_t)g * 16 * NF + kk * 32);
    }

    // xsq preload (13 values per lane; L2-hot)
    float xv[13];
    {
        const float* xs_n = xsq + n * HW;
        #pragma unroll
        for (int mt = 0; mt < 13; ++mt) {
            int hw = mt * 16 + row;
            xv[mt] = (hw < HW) ? xs_n[hw] : 3.0e38f;
        }
    }

    // stage fT[n] (208x128 bf16) into LDS: 13 independent wide loads in flight
    {
        const unsigned short* fb = fT + (size_t)n * MPAD * NF;
        const int srow = t >> 4;           // 0..15
        const int scol = (t & 15) * 8;     // shorts
        uint4 tmp[13];
        #pragma unroll
        for (int i = 0; i < 13; ++i)
            tmp[i] = *(const uint4*)(fb + (size_t)(i * 16 + srow) * NF + scol);
        #pragma unroll
        for (int i = 0; i < 13; ++i)
            *(uint4*)(sf + (i * 16 + srow) * LDS_ROW + scol) = tmp[i];
    }
    __syncthreads();

    float runmin[4][4];
    #pragma unroll
    for (int g = 0; g < 4; ++g)
        #pragma unroll
        for (int r = 0; r < 4; ++r) runmin[g][r] = 3.0e38f;

    #pragma unroll
    for (int mt = 0; mt < 13; ++mt) {
        const unsigned short* bp = sf + (mt * 16 + row) * LDS_ROW + quad * 8;
        short8 bfrag[4];
        #pragma unroll
        for (int kk = 0; kk < 4; ++kk)
            bfrag[kk] = *(const short8*)(bp + kk * 32);

        #pragma unroll
        for (int g = 0; g < 4; ++g) {
            f32x4 acc = {0.f, 0.f, 0.f, 0.f};
            acc = __builtin_amdgcn_mfma_f32_16x16x32_bf16(A[g][0], bfrag[0], acc, 0, 0, 0);
            acc = __builtin_amdgcn_mfma_f32_16x16x32_bf16(A[g][1], bfrag[1], acc, 0, 0, 0);
            acc = __builtin_amdgcn_mfma_f32_16x16x32_bf16(A[g][2], bfrag[2], acc, 0, 0, 0);
            acc = __builtin_amdgcn_mfma_f32_16x16x32_bf16(A[g][3], bfrag[3], acc, 0, 0, 0);
            #pragma unroll
            for (int r = 0; r < 4; ++r)
                runmin[g][r] = fminf(runmin[g][r], xv[mt] - 2.f * acc[r]);
        }
    }

    // min across the 16 D-columns (hw within tile), then epilogue
    #pragma unroll
    for (int g = 0; g < 4; ++g) {
        #pragma unroll
        for (int off = 1; off < 16; off <<= 1)
            #pragma unroll
            for (int r = 0; r < 4; ++r)
                runmin[g][r] = fminf(runmin[g][r], __shfl_xor(runmin[g][r], off, 64));
        if (row == 0) {
            #pragma unroll
            for (int r = 0; r < 4; ++r) {
                int p = pb + g * 16 + quad * 4 + r;
                if (p < NP) {
                    float m = fmaxf(runmin[g][r] + psq[p], 0.f);
                    min_out[(size_t)n * NP + p] = m;
                    sim_out[(size_t)n * NP + p] = logf((m + 1.f) / (m + EPSV));
                }
            }
        }
    }
}

// ---- kernel 2: logits[n][c] = sum_p sim[n][p] * W[c][p] ----------------------
// one wave per (n, c); float4 loads, fully unrolled (2000 = 500 float4)
__global__ __launch_bounds__(256) void klogits(const float* __restrict__ sim,
                                               const float* __restrict__ W,
                                               float* __restrict__ logits) {
    const int n    = blockIdx.x;
    const int wave = threadIdx.x >> 6;
    const int lane = threadIdx.x & 63;
    const int c    = blockIdx.y * 4 + wave;

    const float4* s4 = (const float4*)(sim + (size_t)n * NP);
    const float4* w4 = (const float4*)(W + (size_t)c * NP);

    float acc = 0.f;
    #pragma unroll
    for (int j = 0; j < 8; ++j) {
        int idx = j * 64 + lane;
        if (idx < 500) {
            float4 a = s4[idx];
            float4 b = w4[idx];
            acc += a.x * b.x + a.y * b.y + a.z * b.z + a.w * b.w;
        }
    }
    #pragma unroll
    for (int off = 32; off; off >>= 1) acc += __shfl_down(acc, off, 64);
    if (lane == 0) logits[n * NUM_CLASSES + c] = acc;
}

extern "C" void kernel_launch(void* const* d_in, const int* in_sizes, int n_in,
                              void* d_out, int out_size, void* d_ws, size_t ws_size,
                              hipStream_t stream) {
    const float* f      = (const float*)d_in[0];  // 64x128x14x14
    const float* protos = (const float*)d_in[1];  // 2000x128
    const float* W      = (const float*)d_in[2];  // 200x2000

    float* logits   = (float*)d_out;
    float* min_dist = (float*)d_out + NB * NUM_CLASSES;

    float* xsq = (float*)d_ws;                       // 64*196 f32
    float* psq = xsq + NB * HW;                      // 2048 f32
    float* sim = psq + NP_PAD;                       // 64*2000 f32
    unsigned short* pT = (unsigned short*)(sim + NB * NP);   // 2048*128 bf16
    unsigned short* fT = pT + (size_t)NP_PAD * NF;           // 64*208*128 bf16

    kprep<<<1032, 256, 0, stream>>>(f, protos, xsq, psq, pT, fT);
    kdist<<<dim3(NB, 8), 256, 0, stream>>>(pT, fT, xsq, psq, min_dist, sim);
    klogits<<<dim3(NB, 50), 256, 0, stream>>>(sim, W, logits);
}